// Round 1
// baseline (260.111 us; speedup 1.0000x reference)
//
#include <hip/hip_runtime.h>
#include <stdint.h>

typedef unsigned short u16;
typedef unsigned short bf16x8 __attribute__((ext_vector_type(8)));
typedef unsigned short u16x4 __attribute__((ext_vector_type(4)));
typedef float f32x4 __attribute__((ext_vector_type(4)));

typedef __attribute__((address_space(3))) unsigned int lds_u32;
typedef __attribute__((address_space(1))) unsigned int gbl_u32;

__device__ __forceinline__ u16 f2bf(float f) {
    unsigned u = __builtin_bit_cast(unsigned, f);
    u += 0x7fffu + ((u >> 16) & 1u);
    return (u16)(u >> 16);
}

__device__ __forceinline__ void mfma_bf16(f32x4& d, bf16x8 a, bf16x8 b) {
    asm("v_mfma_f32_16x16x32_bf16 %0, %1, %2, %0" : "+v"(d) : "v"(a), "v"(b));
}

// global -> LDS direct copy, 16B per lane. LDS dest must be wave-uniform base;
// HW adds lane*16. (CK-style integer cast: low 32 bits of flat LDS addr = group offset.)
__device__ __forceinline__ void g2l16(const void* g, void* l) {
    unsigned int loff = (unsigned int)(unsigned long long)l;
    __builtin_amdgcn_global_load_lds(
        reinterpret_cast<gbl_u32*>((unsigned long long)g),
        reinterpret_cast<lds_u32*>(loff), 16, 0, 0);
}

// ---------------- cast f32 -> bf16 (vectorized) ----------------
__global__ __launch_bounds__(256) void cast_bf16_kernel(const float* __restrict__ in,
                                                        u16* __restrict__ out, int n) {
    int i = (blockIdx.x * 256 + threadIdx.x) * 4;
    if (i >= n) return;
    f32x4 v = *reinterpret_cast<const f32x4*>(in + i);
    u16x4 o;
#pragma unroll
    for (int k = 0; k < 4; k++) o[k] = f2bf(v[k]);
    *reinterpret_cast<u16x4*>(out + i) = o;
}

// ---------------- transpose + cast: W[K][N] f32 -> Wt[N][K] bf16 ----------------
__global__ __launch_bounds__(256) void transpose_cast_kernel(const float* __restrict__ W,
                                                             u16* __restrict__ Wt, int K, int N) {
    __shared__ float tile[32][33];
    int n0 = blockIdx.x * 32, k0 = blockIdx.y * 32;
    int tx = threadIdx.x, ty = threadIdx.y;
#pragma unroll
    for (int i = 0; i < 4; i++)
        tile[ty + i * 8][tx] = W[(size_t)(k0 + ty + i * 8) * N + n0 + tx];
    __syncthreads();
#pragma unroll
    for (int i = 0; i < 4; i++)
        Wt[(size_t)(n0 + ty + i * 8) * K + k0 + tx] = f2bf(tile[tx][ty + i * 8]);
}

// ---------------- V transpose: KV[4096][1024] cols 512.. -> Vt[b][hkv][128][2048] ----------------
__global__ __launch_bounds__(256) void vt_transpose_kernel(const u16* __restrict__ KV,
                                                           u16* __restrict__ Vt) {
    __shared__ u16 tile[32][33];
    int s0 = blockIdx.x * 32, d0 = blockIdx.y * 32, bh = blockIdx.z;
    int b = bh >> 2, hkv = bh & 3;
    int tx = threadIdx.x, ty = threadIdx.y;
#pragma unroll
    for (int i = 0; i < 4; i++) {
        int s = s0 + ty + i * 8;
        tile[ty + i * 8][tx] = KV[(size_t)(b * 2048 + s) * 1024 + 512 + hkv * 128 + d0 + tx];
    }
    __syncthreads();
#pragma unroll
    for (int i = 0; i < 4; i++) {
        int d = d0 + ty + i * 8;
        Vt[((size_t)bh * 128 + d) * 2048 + s0 + tx] = tile[tx][ty + i * 8];
    }
}

// ---------------- bf16 GEMM: C[M][N] = A[M][K] * Bt[N][K]^T  (m97 structure) ----------------
template <int OF32>
__global__ __launch_bounds__(256) void gemm_bt_kernel(const u16* __restrict__ A,
                                                      const u16* __restrict__ Bt,
                                                      void* __restrict__ Cout,
                                                      int M, int N, int K) {
    __shared__ u16 lA[128 * 32];
    __shared__ u16 lB[128 * 32];
    int n0 = blockIdx.x * 128, m0 = blockIdx.y * 128;
    int t = threadIdx.x, w = t >> 6, l = t & 63;
    int wm = w >> 1, wn = w & 1;
    int lg = l >> 4, lc = l & 15;

    f32x4 acc[4][4] = {};

    const char* Ab = (const char*)A;
    const char* Bb = (const char*)Bt;

    for (int kt = 0; kt < K; kt += 32) {
        __syncthreads();
        // stage A[128][32], Bt[128][32] -> LDS linear (2 issues each)
#pragma unroll
        for (int i = 0; i < 2; i++) {
            int r = (i * 256 + t) >> 2;
            int innerb = (t & 3) * 16;
            g2l16(Ab + ((size_t)(m0 + r) * K + kt) * 2 + innerb, lA + (i * 256 + w * 64) * 8);
            g2l16(Bb + ((size_t)(n0 + r) * K + kt) * 2 + innerb, lB + (i * 256 + w * 64) * 8);
        }
        __syncthreads();

        bf16x8 af[4], bf[4];
        int ko = lg * 8;
#pragma unroll
        for (int fm = 0; fm < 4; fm++)
            af[fm] = *(const bf16x8*)(lA + (wm * 64 + fm * 16 + lc) * 32 + ko);
#pragma unroll
        for (int fn = 0; fn < 4; fn++)
            bf[fn] = *(const bf16x8*)(lB + (wn * 64 + fn * 16 + lc) * 32 + ko);
#pragma unroll
        for (int fm = 0; fm < 4; fm++)
#pragma unroll
            for (int fn = 0; fn < 4; fn++)
                mfma_bf16(acc[fm][fn], af[fm], bf[fn]);
    }
    asm volatile("s_nop 7\n s_nop 7\n s_nop 7" ::);

#pragma unroll
    for (int fm = 0; fm < 4; fm++)
#pragma unroll
        for (int fn = 0; fn < 4; fn++)
#pragma unroll
            for (int j = 0; j < 4; j++) {
                int r = m0 + wm * 64 + fm * 16 + lg * 4 + j;
                int c = n0 + wn * 64 + fn * 16 + lc;
                if (OF32)
                    ((float*)Cout)[(size_t)r * N + c] = acc[fm][fn][j];
                else
                    ((u16*)Cout)[(size_t)r * N + c] = f2bf(acc[fm][fn][j]);
            }
}

// ---------------- flash attention, windowed causal (W=1024) ----------------
// grid: b(2) * h(16) * qtile(32); block 256 = 4 waves, each wave 16 q-rows.
__global__ __launch_bounds__(256) void attn_kernel(const u16* __restrict__ Q,
                                                   const u16* __restrict__ KV,
                                                   const u16* __restrict__ Vt,
                                                   u16* __restrict__ AO) {
    __shared__ u16 lK[64 * 128];   // K tile, 256B rows, XOR-swizzled
    __shared__ u16 lV[128 * 64];   // Vt tile, 128B rows, XOR-swizzled
    __shared__ u16 lP[4 * 16 * 64];// per-wave P, 128B rows, XOR-swizzled

    int bid = blockIdx.x;
    int qt = bid & 31, h = (bid >> 5) & 15, b = bid >> 9;
    int hkv = h >> 2;
    int q0 = qt * 64;
    int t = threadIdx.x, w = t >> 6, l = t & 63;
    int lg = l >> 4, lc = l & 15;

    // Q fragments (A-layout: row = lc, k = lg*8+j + 32*ks), kept in registers
    bf16x8 qf[4];
    {
        const u16* qrow = Q + (size_t)(b * 2048 + q0 + w * 16 + lc) * 2048 + h * 128;
#pragma unroll
        for (int ks = 0; ks < 4; ks++)
            qf[ks] = *(const bf16x8*)(qrow + ks * 32 + lg * 8);
    }

    f32x4 acc[8] = {};          // O accum: fn = d-block 0..7; rows lg*4+j
    float mrow[4], lrow[4];
#pragma unroll
    for (int j = 0; j < 4; j++) { mrow[j] = -INFINITY; lrow[j] = 0.0f; }

    int t0 = (qt > 16) ? (qt - 16) : 0;
    for (int kt = t0; kt <= qt; kt++) {
        int ks0 = kt * 64;
        __syncthreads();  // previous iteration's LDS reads done
        // stage K tile [64][128] (pre-swizzled global source -> linear LDS)
#pragma unroll
        for (int i = 0; i < 4; i++) {
            int L = (i * 256 + t) * 16;
            int r = L >> 8, inner = L & 255;
            const char* g = (const char*)KV +
                ((size_t)(b * 2048 + ks0 + r) * 1024 + hkv * 128) * 2 + (inner ^ ((r & 7) << 4));
            g2l16(g, (char*)lK + (i * 256 + w * 64) * 16);
        }
        // stage Vt tile [128][64]
#pragma unroll
        for (int i = 0; i < 4; i++) {
            int L = (i * 256 + t) * 16;
            int r = L >> 7, inner = L & 127;
            const char* g = (const char*)Vt +
                ((size_t)((b * 4 + hkv) * 128 + r) * 2048 + ks0) * 2 + (inner ^ ((r & 7) << 4));
            g2l16(g, (char*)lV + (i * 256 + w * 64) * 16);
        }
        __syncthreads();  // staging complete

        // QK^T : sacc[fn] covers keys ks0 + fn*16 + lc, rows lg*4+j
        f32x4 sacc[4] = {};
        asm volatile("s_nop 7" ::);
#pragma unroll
        for (int fn = 0; fn < 4; fn++) {
#pragma unroll
            for (int ks = 0; ks < 4; ks++) {
                int srow = fn * 16 + lc;
                int boff = (ks * 64 + lg * 16) ^ ((srow & 7) << 4);
                bf16x8 kf = *(const bf16x8*)((const char*)lK + srow * 256 + boff);
                mfma_bf16(sacc[fn], qf[ks], kf);
            }
        }
        asm volatile("s_nop 7\n s_nop 7" ::);

        // mask + online softmax
        float p[4][4];
#pragma unroll
        for (int j = 0; j < 4; j++) {
            int qrow = q0 + w * 16 + lg * 4 + j;
            float sv[4];
            float mx = -INFINITY;
#pragma unroll
            for (int fn = 0; fn < 4; fn++) {
                int key = ks0 + fn * 16 + lc;
                float s = sacc[fn][j] * 0.08838834764831845f;  // 1/sqrt(128)
                bool valid = (key <= qrow) && (key + 1024 >= qrow);
                sv[fn] = valid ? s : -INFINITY;
                mx = fmaxf(mx, sv[fn]);
            }
#pragma unroll
            for (int m = 1; m < 16; m <<= 1) mx = fmaxf(mx, __shfl_xor(mx, m, 64));
            float mnew = fmaxf(mrow[j], mx);
            float muse = fmaxf(mnew, -1e30f);
            float fac = __expf(mrow[j] - muse);
            mrow[j] = mnew;
            float psum = 0.0f;
#pragma unroll
            for (int fn = 0; fn < 4; fn++) {
                float pv = __expf(sv[fn] - muse);
                p[fn][j] = pv;
                psum += pv;
            }
#pragma unroll
            for (int m = 1; m < 16; m <<= 1) psum += __shfl_xor(psum, m, 64);
            lrow[j] = lrow[j] * fac + psum;
#pragma unroll
            for (int fn = 0; fn < 8; fn++) acc[fn][j] *= fac;
        }

        // write P (bf16) to per-wave LDS region, swizzled
#pragma unroll
        for (int fn = 0; fn < 4; fn++)
#pragma unroll
            for (int j = 0; j < 4; j++) {
                int r = lg * 4 + j;
                int cb = (fn * 16 + lc) * 2;
                *(u16*)((char*)lP + w * 2048 + r * 128 + (cb ^ ((r & 7) << 4))) = f2bf(p[fn][j]);
            }
        __syncthreads();  // P visible (also fences lK/lV read completion ordering)

        // PV: acc[fn] += P[16x64] * V[64x(fn*16..)]
        asm volatile("s_nop 7" ::);
#pragma unroll
        for (int kk = 0; kk < 2; kk++) {
            int pboff = (kk * 64 + lg * 16) ^ ((lc & 7) << 4);
            bf16x8 pf = *(const bf16x8*)((const char*)lP + w * 2048 + lc * 128 + pboff);
#pragma unroll
            for (int fn = 0; fn < 8; fn++) {
                int vrow = fn * 16 + lc;
                int vboff = (kk * 64 + lg * 16) ^ ((vrow & 7) << 4);
                bf16x8 vf = *(const bf16x8*)((const char*)lV + vrow * 128 + vboff);
                mfma_bf16(acc[fn], pf, vf);
            }
        }
    }
    asm volatile("s_nop 7\n s_nop 7" ::);

    // epilogue: normalize and store
#pragma unroll
    for (int j = 0; j < 4; j++) {
        float inv = 1.0f / lrow[j];
        size_t base = (size_t)(b * 2048 + q0 + w * 16 + lg * 4 + j) * 2048 + h * 128;
#pragma unroll
        for (int fn = 0; fn < 8; fn++)
            AO[base + fn * 16 + lc] = f2bf(acc[fn][j] * inv);
    }
}

// ---------------- launcher ----------------
extern "C" void kernel_launch(void* const* d_in, const int* in_sizes, int n_in,
                              void* d_out, int out_size, void* d_ws, size_t ws_size,
                              hipStream_t stream) {
    const float* hs = (const float*)d_in[0];
    const float* Wq = (const float*)d_in[1];
    const float* Wk = (const float*)d_in[2];
    const float* Wv = (const float*)d_in[3];
    const float* Wo = (const float*)d_in[4];
    float* out = (float*)d_out;

    // workspace layout (u16 elements), 60 MiB total with two aliased regions
    u16* ws = (u16*)d_ws;
    u16* hsB  = ws;                      // 8,388,608   (reused as AO after GEMMs)
    u16* WqT  = hsB + 8388608;           // 4,194,304   (reused as Vt after Q GEMM)
    u16* WkvT = WqT + 4194304;           // 2,097,152   [1024][2048]
    u16* WoT  = WkvT + 2097152;          // 4,194,304
    u16* Qb   = WoT + 4194304;           // 8,388,608   [4096][2048]
    u16* KVb  = Qb + 8388608;            // 4,194,304   [4096][1024]
    u16* Vtb  = WqT;                     // alias: needs 2,097,152
    u16* AOb  = hsB;                     // alias: needs 8,388,608

    // 1) casts / transposes
    cast_bf16_kernel<<<8192, 256, 0, stream>>>(hs, hsB, 8388608);
    transpose_cast_kernel<<<dim3(64, 64), dim3(32, 8), 0, stream>>>(Wq, WqT, 2048, 2048);
    transpose_cast_kernel<<<dim3(16, 64), dim3(32, 8), 0, stream>>>(Wk, WkvT, 2048, 512);
    transpose_cast_kernel<<<dim3(16, 64), dim3(32, 8), 0, stream>>>(Wv, WkvT + (size_t)512 * 2048, 2048, 512);
    transpose_cast_kernel<<<dim3(64, 64), dim3(32, 8), 0, stream>>>(Wo, WoT, 2048, 2048);

    // 2) projections
    gemm_bt_kernel<0><<<dim3(16, 32), 256, 0, stream>>>(hsB, WqT, Qb, 4096, 2048, 2048);
    gemm_bt_kernel<0><<<dim3(8, 32), 256, 0, stream>>>(hsB, WkvT, KVb, 4096, 1024, 2048);

    // 3) V transpose for PV B-operand
    vt_transpose_kernel<<<dim3(64, 4, 8), dim3(32, 8), 0, stream>>>(KVb, Vtb);

    // 4) windowed causal flash attention
    attn_kernel<<<1024, 256, 0, stream>>>(Qb, KVb, Vtb, AOb);

    // 5) output projection -> f32
    gemm_bt_kernel<1><<<dim3(16, 32), 256, 0, stream>>>(AOb, WoT, out, 4096, 2048, 2048);
}